// Round 3
// baseline (68.444 us; speedup 1.0000x reference)
//
#include <hip/hip_runtime.h>

#define ALPHA 0.2f

__device__ __forceinline__ float leaky(float x){ return x > 0.f ? x : ALPHA * x; }
__device__ __forceinline__ float elu1 (float x){ return x > 0.f ? x : (__expf(x) - 1.f); }

// One block per (n, t'). 192 blocks, 512 threads (8 waves -> 2 waves/SIMD).
// GEMM: lane-resident W column (global, VMEM pipe) x LDS-broadcast X rows.
// out = [ elu(h_prime) : 16*12*64*64 ][ attention : 16*12*64*64 ]  (f32)
__global__ __launch_bounds__(512) void gat_fused(
    const float* __restrict__ inp,   // [16,12,64,64]
    const float* __restrict__ W,     // [64,64]
    const float* __restrict__ av,    // [128]  (a[:,0])
    float* __restrict__ out)
{
    __shared__ __align__(16) float Ws[64*68];   // W (for Wa only)
    __shared__ __align__(16) float X [64*68];   // own inp tile; reused as Hsum (t'>=6)
    __shared__ __align__(16) float H [64*68];   // h = X @ W
    __shared__ __align__(16) float aL[128];
    __shared__ __align__(16) float WaA[64], WaB[64], Wa1[64];
    __shared__ float sArr[2][64];               // per-tt row dots
    __shared__ __align__(16) float S0L[64], S1L[64];
    __shared__ __align__(16) float attL[2][32];
    __shared__ __align__(16) float eluL[2][64];

    const int bid = blockIdx.x;
    const int nI  = bid / 12;
    const int tP  = bid - nI * 12;
    const int tid = threadIdx.x;
    const int lane = tid & 63;
    const int wvid = tid >> 6;

    const bool firstHalf = (tP < 6);
    const int tt0 = firstHalf ? 2*tP : 2*tP - 12;

    const size_t ownBase = (size_t)(nI*12 + tP) * 4096;

    // ---- W column -> registers (VMEM pipe; identical addrs across waves -> L1) ----
    float wreg[64];
    #pragma unroll
    for (int c = 0; c < 64; ++c) wreg[c] = W[c*64 + lane];

    // ---- cross-slice row prefetch (HBM-cold latency hides under staging/Wa) ----
    float4 rr[16];
    if (tid < 128) {
        const int q  = tid >> 6, vvl = tid & 63;
        const float4* xr = (const float4*)(inp + (size_t)(nI*12 + tt0 + q)*4096 + vvl*64);
        #pragma unroll
        for (int u = 0; u < 16; ++u) rr[u] = xr[u];
    }

    // ---- global -> LDS staging ----
    const float4* W4 = (const float4*)W;
    const float4* X4 = (const float4*)(inp + ownBase);
    #pragma unroll
    for (int i = tid; i < 1024; i += 512) {
        const int r = i >> 4, c4 = (i & 15) << 2;
        *(float4*)&Ws[r*68 + c4] = W4[i];
        *(float4*)&X [r*68 + c4] = X4[i];
    }
    if (tid < 128) aL[tid] = av[tid];
    __syncthreads();

    // ---- Wa vectors (wave 0) ----
    if (tid < 64) {
        const float4* wr4 = (const float4*)&Ws[tid*68];
        const float4* a4  = (const float4*)aL;
        float sA = 0.f, sB = 0.f;
        #pragma unroll
        for (int u = 0; u < 16; ++u) {
            const float4 w = wr4[u], x = a4[u], y = a4[u+16];
            sA += w.x*x.x + w.y*x.y + w.z*x.z + w.w*x.w;
            sB += w.x*y.x + w.y*y.y + w.z*y.z + w.w*y.w;
        }
        WaA[tid] = sA; WaB[tid] = sB; Wa1[tid] = sA + sB;
    }
    __syncthreads();

    // ---- dots from prefetched regs (waves 0-1); rr dies here ----
    if (tid < 128) {
        const int q = tid >> 6, vvl = tid & 63;
        const float* wvp = firstHalf ? Wa1 : ((vvl & 1) ? WaB : WaA);
        const float4* wv4 = (const float4*)wvp;
        float s = 0.f;
        #pragma unroll
        for (int u = 0; u < 16; ++u) {
            const float4 x = rr[u], w = wv4[u];
            s += x.x*w.x + x.y*w.y + x.z*w.z + x.w*w.w;
        }
        sArr[q][vvl] = s;
    }

    // ---- h = X @ W : wave -> rows 8w..8w+7, lane -> column ----
    {
        const int vbase = wvid * 8;
        float acc[8];
        #pragma unroll
        for (int r = 0; r < 8; ++r) acc[r] = 0.f;
        #pragma unroll
        for (int c0 = 0; c0 < 64; c0 += 4) {
            #pragma unroll
            for (int r = 0; r < 8; ++r) {
                const float4 xb = *(const float4*)&X[(vbase + r)*68 + c0];  // broadcast
                acc[r] += xb.x*wreg[c0] + xb.y*wreg[c0+1] + xb.z*wreg[c0+2] + xb.w*wreg[c0+3];
            }
        }
        #pragma unroll
        for (int r = 0; r < 8; ++r) H[(vbase + r)*68 + lane] = acc[r];
    }
    __syncthreads();

    float* out1 = out + ownBase;            // elu(h_prime)
    float* out2 = out + 786432 + ownBase;   // attention

    if (firstHalf) {
        // column sums of H halves (wave 0)
        if (tid < 64) {
            const int k = tid;
            float s0 = 0.f, s1 = 0.f;
            #pragma unroll
            for (int w = 0; w < 32; ++w) { s0 += H[w*68 + k]; s1 += H[(w+32)*68 + k]; }
            S0L[k] = s0; S1L[k] = s1;
        }
        __syncthreads();
        const int v = tid >> 3, tk = tid & 7;
        const int q = v >> 5, vp = v & 31;
        const float A = leaky(sArr[q][2*vp]);
        const float B = leaky(sArr[q][2*vp + 1]);
        const float m  = fmaxf(A, B);
        const float eA = __expf(A - m), eB = __expf(B - m);
        const float inv = 1.f / (32.f * (eA + eB));
        const float pA = eA * inv, pB = eB * inv;
        const int k0 = tk * 8;
        const float4 s00 = *(const float4*)&S0L[k0],     s01 = *(const float4*)&S0L[k0+4];
        const float4 s10 = *(const float4*)&S1L[k0],     s11 = *(const float4*)&S1L[k0+4];
        float4 r0, r1;
        r0.x = elu1(pA*s00.x + pB*s10.x);
        r0.y = elu1(pA*s00.y + pB*s10.y);
        r0.z = elu1(pA*s00.z + pB*s10.z);
        r0.w = elu1(pA*s00.w + pB*s10.w);
        r1.x = elu1(pA*s01.x + pB*s11.x);
        r1.y = elu1(pA*s01.y + pB*s11.y);
        r1.z = elu1(pA*s01.z + pB*s11.z);
        r1.w = elu1(pA*s01.w + pB*s11.w);
        float4* o1 = (float4*)(out1 + v*64 + k0);
        o1[0] = r0; o1[1] = r1;
        const float pv = (tk < 4) ? pA : pB;
        const float4 p4 = make_float4(pv, pv, pv, pv);
        float4* o2 = (float4*)(out2 + v*64 + k0);
        o2[0] = p4; o2[1] = p4;
    } else {
        // softmax (wave 0) || Hsum into X (waves 2-5)
        if (tid < 64) {
            const int q = tid >> 5, wp = tid & 31;
            float cv = leaky(sArr[q][2*wp] + sArr[q][2*wp + 1]);
            float m = cv;
            #pragma unroll
            for (int mask = 16; mask; mask >>= 1) m = fmaxf(m, __shfl_xor(m, mask));
            const float e = __expf(cv - m);
            float s = e;
            #pragma unroll
            for (int mask = 16; mask; mask >>= 1) s += __shfl_xor(s, mask);
            attL[q][wp] = e / (2.f * s);
        } else if (tid >= 128 && tid < 384) {
            const int idx = tid - 128;
            const int wp = idx >> 3, k0 = (idx & 7) * 8;
            const float4* h0 = (const float4*)&H[wp*68 + k0];
            const float4* h1 = (const float4*)&H[(wp+32)*68 + k0];
            const float4 u0 = h0[0], u1 = h0[1], v0 = h1[0], v1 = h1[1];
            *(float4*)&X[wp*68 + k0]     = make_float4(u0.x+v0.x, u0.y+v0.y, u0.z+v0.z, u0.w+v0.w);
            *(float4*)&X[wp*68 + k0 + 4] = make_float4(u1.x+v1.x, u1.y+v1.y, u1.z+v1.z, u1.w+v1.w);
        }
        __syncthreads();
        // h_prime rows (one per q) from Hsum
        if (tid < 128) {
            const int q = tid >> 6, k = tid & 63;
            float acc = 0.f;
            #pragma unroll
            for (int wp = 0; wp < 32; ++wp)
                acc += attL[q][wp] * X[wp*68 + k];
            eluL[q][k] = elu1(acc);
        }
        __syncthreads();
        const int v = tid >> 3, tk = tid & 7;
        const int q = v >> 5;
        const int k0 = tk * 8;
        const float4* s1 = (const float4*)&eluL[q][k0];
        float4* o1 = (float4*)(out1 + v*64 + k0);
        o1[0] = s1[0]; o1[1] = s1[1];
        const float4* s2 = (const float4*)&attL[q][(tk & 3)*8];
        float4* o2 = (float4*)(out2 + v*64 + k0);
        o2[0] = s2[0]; o2[1] = s2[1];
    }
}

extern "C" void kernel_launch(void* const* d_in, const int* in_sizes, int n_in,
                              void* d_out, int out_size, void* d_ws, size_t ws_size,
                              hipStream_t stream) {
    const float* inp = (const float*)d_in[0];
    // d_in[1] = adj — dead code in the reference (both branches set attention = e)
    const float* W   = (const float*)d_in[2];
    const float* av  = (const float*)d_in[3];
    float* out = (float*)d_out;
    gat_fused<<<dim3(192), dim3(512), 0, stream>>>(inp, W, av, out);
}